// Round 5
// baseline (421.933 us; speedup 1.0000x reference)
//
#include <hip/hip_runtime.h>
#include <math.h>

#define HH 1024
#define VV 50000
#define NW2 6250           // K2 active waves: 8 rows each (4 + 4 at +25000)
#define NB2 1563           // ceil(6250/4) blocks; block 1562 has 2 idle waves

typedef float f4 __attribute__((ext_vector_type(4)));

__device__ __forceinline__ float dot4(f4 a, f4 b) {
    return a.x * b.x + a.y * b.y + a.z * b.z + a.w * b.w;
}

// ---------------------------------------------------------------------------
// K1: LSTM cell. block = hidden index j (1024 blocks), wave = gate g (4 waves).
// Plain cached loads (L3 retains ~half the weights across the harness fills —
// round-2 FETCH evidence); nt loads regressed.
// ---------------------------------------------------------------------------
__global__ __launch_bounds__(256) void lstm_kernel(
    const int* __restrict__ tok, const float* __restrict__ emb,
    const float* __restrict__ h0, const float* __restrict__ c0,
    const float* __restrict__ W_ih, const float* __restrict__ W_hh,
    const float* __restrict__ b_ih, const float* __restrict__ b_hh,
    float* __restrict__ out)      // d_out: [V logits][H h_new][H c_new]
{
    __shared__ float sg[4];
    const int g    = threadIdx.x >> 6;               // gate = wave id
    const int lane = threadIdx.x & 63;
    const int j    = blockIdx.x;                     // 0..1023
    const int t    = tok[0];                         // int64 low word
    const float* e = emb + (size_t)t * HH;

    const float* wi = W_ih + (size_t)(g * HH + j) * HH;
    const float* wh = W_hh + (size_t)(g * HH + j) * HH;

    float acc = 0.f;
#pragma unroll
    for (int k = 0; k < 4; ++k) {
        const int idx = k * 256 + lane * 4;
        const f4 a  = *(const f4*)(wi + idx);
        const f4 b  = *(const f4*)(wh + idx);
        const f4 ev = *(const f4*)(e  + idx);
        const f4 hv = *(const f4*)(h0 + idx);
        acc += dot4(a, ev);
        acc += dot4(b, hv);
    }
#pragma unroll
    for (int o = 32; o > 0; o >>= 1) acc += __shfl_xor(acc, o);
    if (lane == 0) sg[g] = acc + b_ih[g * HH + j] + b_hh[g * HH + j];
    __syncthreads();

    if (threadIdx.x == 0) {
        const float si = 1.f / (1.f + expf(-sg[0]));
        const float sf = 1.f / (1.f + expf(-sg[1]));
        const float gg = tanhf(sg[2]);
        const float so = 1.f / (1.f + expf(-sg[3]));
        const float cn = sf * c0[j] + si * gg;
        const float hn = so * tanhf(cn);
        out[VV + j]      = hn;
        out[VV + HH + j] = cn;
    }
}

// ---------------------------------------------------------------------------
// K2: logits = out_W·h + out_b. 8 rows/wave in TWO groups of 4 consecutive
// rows (rA = 4*gw, rB = rA + 25000). All 32 loads issued up front; group A's
// butterfly reduction (shuffle/VALU only, no vmcnt dependency) overlaps
// group B's loads still in flight. ~128 VGPRs of load data -> ~8 waves/CU,
// 8 x 16 KB = 128 KB in flight per CU >> Little's-law 9.2 KB requirement.
// ---------------------------------------------------------------------------
__global__ __launch_bounds__(256) void logits_kernel(
    const float* __restrict__ out_W, const float* __restrict__ out_b,
    const float* __restrict__ h,      // = d_out + V (written by K1)
    float* __restrict__ logits,       // = d_out
    float2* __restrict__ part)        // [NB2] (m_b, s_b)
{
    __shared__ float2 sp[4];
    const int wid  = threadIdx.x >> 6;
    const int lane = threadIdx.x & 63;
    const int gw   = blockIdx.x * 4 + wid;           // 0..6255 (>=6250 idle)

    if (gw < NW2) {
        f4 hv[4];
#pragma unroll
        for (int k = 0; k < 4; ++k)
            hv[k] = *(const f4*)(h + k * 256 + lane * 4);

        const int rA = gw * 4;
        const int rB = rA + 25000;

        // ---- issue all 32 independent 1-KB loads ---------------------------
        f4 xa[16], xb[16];
#pragma unroll
        for (int j = 0; j < 4; ++j) {
            const f4* w = (const f4*)(out_W + (size_t)(rA + j) * HH);
            xa[4*j+0] = w[lane];       xa[4*j+1] = w[lane + 64];
            xa[4*j+2] = w[lane + 128]; xa[4*j+3] = w[lane + 192];
        }
#pragma unroll
        for (int j = 0; j < 4; ++j) {
            const f4* w = (const f4*)(out_W + (size_t)(rB + j) * HH);
            xb[4*j+0] = w[lane];       xb[4*j+1] = w[lane + 64];
            xb[4*j+2] = w[lane + 128]; xb[4*j+3] = w[lane + 192];
        }

        // ---- group A dots + reduce (overlaps B loads in flight) ------------
        float accA[4], accB[4];
#pragma unroll
        for (int j = 0; j < 4; ++j)
            accA[j] = (dot4(xa[4*j+0], hv[0]) + dot4(xa[4*j+1], hv[1]))
                    + (dot4(xa[4*j+2], hv[2]) + dot4(xa[4*j+3], hv[3]));
#pragma unroll
        for (int o = 32; o > 0; o >>= 1) {
#pragma unroll
            for (int j = 0; j < 4; ++j) accA[j] += __shfl_xor(accA[j], o);
        }

        // ---- group B dots + reduce -----------------------------------------
#pragma unroll
        for (int j = 0; j < 4; ++j)
            accB[j] = (dot4(xb[4*j+0], hv[0]) + dot4(xb[4*j+1], hv[1]))
                    + (dot4(xb[4*j+2], hv[2]) + dot4(xb[4*j+3], hv[3]));
#pragma unroll
        for (int o = 32; o > 0; o >>= 1) {
#pragma unroll
            for (int j = 0; j < 4; ++j) accB[j] += __shfl_xor(accB[j], o);
        }

        // ---- bias, store, max/sumexp ---------------------------------------
        const f4 ba = *(const f4*)(out_b + rA);
        const f4 bb = *(const f4*)(out_b + rB);
        accA[0] += ba.x; accA[1] += ba.y; accA[2] += ba.z; accA[3] += ba.w;
        accB[0] += bb.x; accB[1] += bb.y; accB[2] += bb.z; accB[3] += bb.w;
        if (lane == 0) {
            f4 st;
            st.x = accA[0]; st.y = accA[1]; st.z = accA[2]; st.w = accA[3];
            *(f4*)(logits + rA) = st;
            st.x = accB[0]; st.y = accB[1]; st.z = accB[2]; st.w = accB[3];
            *(f4*)(logits + rB) = st;
        }
        const float mA = fmaxf(fmaxf(accA[0], accA[1]), fmaxf(accA[2], accA[3]));
        const float mB = fmaxf(fmaxf(accB[0], accB[1]), fmaxf(accB[2], accB[3]));
        const float m  = fmaxf(mA, mB);
        const float s  = expf(accA[0] - m) + expf(accA[1] - m)
                       + expf(accA[2] - m) + expf(accA[3] - m)
                       + expf(accB[0] - m) + expf(accB[1] - m)
                       + expf(accB[2] - m) + expf(accB[3] - m);
        if (lane == 0) sp[wid] = make_float2(m, s);
    } else if (lane == 0) {
        sp[wid] = make_float2(-INFINITY, 0.f);       // identity partial
    }
    __syncthreads();

    if (threadIdx.x == 0) {
        float2 p = sp[0];                             // wave 0 always valid
#pragma unroll
        for (int w = 1; w < 4; ++w) {
            const float2 q = sp[w];
            const float nm = fmaxf(p.x, q.x);         // q.x=-inf -> nm=p.x,
            p.y = p.y * expf(p.x - nm) + q.y * expf(q.x - nm);  // q adds 0
            p.x = nm;
        }
        part[blockIdx.x] = p;
    }
}

// ---------------------------------------------------------------------------
// K3: merged logZ + subtract. Each of the 49 blocks REDUNDANTLY merges the
// 1563 partials (12.5 KB, L2-hot) -> logZ, then subtracts from its f4 slice.
// ---------------------------------------------------------------------------
__global__ __launch_bounds__(256) void logz_sub_kernel(
    const float2* __restrict__ part, f4* __restrict__ logits)
{
    __shared__ float2 red[256];
    float m = -INFINITY, s = 0.f;
    for (int i = threadIdx.x; i < NB2; i += 256) {
        const float2 q = part[i];
        const float nm = fmaxf(m, q.x);
        s = s * expf(m - nm) + q.y * expf(q.x - nm);
        m = nm;
    }
    red[threadIdx.x] = make_float2(m, s);
    __syncthreads();
    for (int st = 128; st > 0; st >>= 1) {
        if (threadIdx.x < st) {
            float2 p = red[threadIdx.x], q = red[threadIdx.x + st];
            const float nm = fmaxf(p.x, q.x);
            p.y = p.y * expf(p.x - nm) + q.y * expf(q.x - nm);
            p.x = nm;
            red[threadIdx.x] = p;
        }
        __syncthreads();
    }
    const float lz = red[0].x + logf(red[0].y);

    const int v = blockIdx.x * 256 + threadIdx.x;
    if (v < VV / 4) {
        f4 t = logits[v];
        t.x -= lz; t.y -= lz; t.z -= lz; t.w -= lz;
        logits[v] = t;
    }
}

extern "C" void kernel_launch(void* const* d_in, const int* in_sizes, int n_in,
                              void* d_out, int out_size, void* d_ws, size_t ws_size,
                              hipStream_t stream) {
    const int*   tok   = (const int*)  d_in[0];
    const float* h0    = (const float*)d_in[1];
    const float* c0    = (const float*)d_in[2];
    // d_in[3] encoder_outputs — dead code, never read
    const float* emb   = (const float*)d_in[4];
    // d_in[5..8] attn_W, attn_b, comb_W, comb_b — dead code, never read
    const float* W_ih  = (const float*)d_in[9];
    const float* W_hh  = (const float*)d_in[10];
    const float* b_ih  = (const float*)d_in[11];
    const float* b_hh  = (const float*)d_in[12];
    const float* out_W = (const float*)d_in[13];
    const float* out_b = (const float*)d_in[14];

    float* out = (float*)d_out;

    float2* part = (float2*)d_ws;             // [NB2] (m_b, s_b) partials

    lstm_kernel<<<1024, 256, 0, stream>>>(tok, emb, h0, c0, W_ih, W_hh,
                                          b_ih, b_hh, out);
    logits_kernel<<<NB2, 256, 0, stream>>>(out_W, out_b, out + VV, out, part);
    logz_sub_kernel<<<(VV / 4 + 255) / 256, 256, 0, stream>>>(part, (f4*)out);
}